// Round 1
// 1066.478 us; speedup vs baseline: 1.0715x; 1.0715x over previous
//
#include <hip/hip_runtime.h>

// ---------------- problem dims (fixed by setup_inputs) ----------------
#define B_    4
#define T_    4096
#define DD_   1024
#define N_    1024
#define K3_   3072
#define M_    16384      // B_*T_
#define CL_   16         // scan chunk length (time steps)
#define SROWS_ 2048      // stripe rows (one stripe = half a batch, aligned)
#define NSTRIPE_ (M_/SROWS_)     // 8
#define CPS_  (SROWS_/CL_)       // 128 chunks per stripe
#define MEG_  1048576

// ---------------- ws layout (float offsets), total ~47.6 MiB ----------------
// rawS (24 MiB) is aliased by the sigma phase: G0 (2M f) | hiW (1M f) | loW (1M f).
// usS (8 MiB) is aliased by the sigma phase: SbfA (2M shorts) | SbfB (2M shorts).
#define OFF_RAWS  ((size_t)0)                        // 6M f   (24 MiB)
#define OFF_USS   ((size_t)6*MEG_)                   // 2M f   (8 MiB)
#define OFF_UBF   ((size_t)8*MEG_)                   // 1M f = 2M shorts (u stripe bf16; later y_hat bf16)
#define OFF_WCAT  ((size_t)9*MEG_)                   // 2M f = 4M shorts (W_in rows then Wp rows)
#define OFF_WOUTB ((size_t)11*MEG_)                  // 512K f = 1M shorts
#define OFF_AGA   (OFF_WOUTB + 524288)               // 128K f
#define OFF_AGB   (OFF_AGA + 131072)
#define OFF_PRE   (OFF_AGB + 131072)
#define OFF_CARRY (OFF_PRE + 131072)                 // 4096 f
#define OFF_V0    (OFF_CARRY + 4096)                 // 2048 f (2 z)
#define OFF_W1    (OFF_V0 + 2048)
#define OFF_W2    (OFF_W1 + 2048)
#define OFF_TR    (OFF_W2 + 2048)                    // 16 f (unused, kept for layout)
#define OFF_SCAL  (OFF_TR + 16)                      // [0]=inv_in, [1]=inv_out
#define REQ_FLOATS (OFF_SCAL + 16)

typedef short s8v __attribute__((ext_vector_type(8)));   // 8 bf16 (4 VGPRs)
typedef float f4v __attribute__((ext_vector_type(4)));   // MFMA acc

typedef __attribute__((address_space(3))) unsigned int       lds_u32;
typedef const __attribute__((address_space(1))) unsigned int glb_u32;

__device__ __forceinline__ void gload_lds16(const void* g, void* l)
{
    __builtin_amdgcn_global_load_lds((glb_u32*)g, (lds_u32*)l, 16, 0, 0);
}

// fp32 -> bf16 round-to-nearest-even
__device__ __forceinline__ unsigned short f2bf(float f)
{
    unsigned u = __float_as_uint(f);
    u += 0x7FFFu + ((u >> 16) & 1u);
    return (unsigned short)(u >> 16);
}
__device__ __forceinline__ float bf2f(unsigned short h)
{
    return __uint_as_float((unsigned)h << 16);
}

// ---------------- fallback: zero a float buffer ----------------
__global__ void zero_out(float* __restrict__ y, int n)
{
    int i = blockIdx.x * 256 + threadIdx.x;
    if (i < n) y[i] = 0.f;
}

// ---------------- one-time weight conversion to bf16 ----------------
__global__ void cvt_weights(const float* __restrict__ Win, const float* __restrict__ Wp,
                            const float* __restrict__ Wout,
                            unsigned short* __restrict__ Wcat,
                            unsigned short* __restrict__ Woutb)
{
    int i = blockIdx.x * 256 + threadIdx.x;        // 0 .. 5M-1
    if (i < 1048576)       Wcat[i] = f2bf(Win[i]);
    else if (i < 4194304)  Wcat[i] = f2bf(Wp[i - 1048576]);
    else if (i < 5242880)  Woutb[i - 4194304] = f2bf(Wout[i - 4194304]);
}

// ---------------- per-stripe u conversion ----------------
__global__ void cvt_u(const float* __restrict__ src, unsigned short* __restrict__ dst)
{
    int i = blockIdx.x * 256 + threadIdx.x;        // 0 .. 2M-1
    dst[i] = f2bf(src[i]);
}

// ------- split-bf16: w = hi + lo (each bf16), residual ~2^-18 rel -------
// i < 1M -> W_in (z=0), else W_out (z=1); hi/lo laid out [z][1M].
__global__ void split_w(const float* __restrict__ Win, const float* __restrict__ Wout,
                        unsigned short* __restrict__ hi, unsigned short* __restrict__ lo)
{
    int i = blockIdx.x * 256 + threadIdx.x;        // 0 .. 2M-1
    float w = (i < MEG_) ? Win[i] : Wout[i - MEG_];
    unsigned short h = f2bf(w);
    hi[i] = h;
    lo[i] = f2bf(w - bf2f(h));                     // w - hi exact in fp32
}

// =====================================================================
// Split-bf16 MFMA gram: C[z] = W[z] W[z]^T computed as
//   hi.hi^T + hi.lo^T + lo.hi^T  (lo.lo dropped, ~2^-36 of diag).
// 128x128 tile, BK=32, 4 waves 2x2 x (4x4 mfma_16x16x32). Writes fp32 C
// (for the Rayleigh quotient) AND a bf16 copy Cb (squaring-chain seed).
// =====================================================================
__global__ __launch_bounds__(256, 2) void gram_bf16x2(
    const unsigned short* __restrict__ hi, const unsigned short* __restrict__ lo,
    float* __restrict__ C, unsigned short* __restrict__ Cb)
{
    __shared__ __align__(16) unsigned short Ah[128 * 32];
    __shared__ __align__(16) unsigned short Al[128 * 32];
    __shared__ __align__(16) unsigned short Bh[128 * 32];
    __shared__ __align__(16) unsigned short Bl[128 * 32];
    const int tid = threadIdx.x;
    const int z   = blockIdx.z;
    const int m0  = blockIdx.y * 128;
    const int n0  = blockIdx.x * 128;

    const unsigned short* hz = hi + (size_t)z * MEG_;
    const unsigned short* lz = lo + (size_t)z * MEG_;

    const int lane = tid & 63;
    const int w    = tid >> 6;
    const int wm   = (w >> 1) * 64;
    const int wn   = (w & 1) * 64;
    const int lrow = lane & 15;
    const int quad = lane >> 4;
    const int srow = lane >> 2;
    const int scol = (lane & 3) * 8;

    const size_t arow = (size_t)(m0 + w*32 + srow) * 1024 + scol;
    const size_t brow = (size_t)(n0 + w*32 + srow) * 1024 + scol;
    unsigned short* dA0 = &Ah[(w*32     ) * 32];
    unsigned short* dA1 = &Ah[(w*32 + 16) * 32];
    unsigned short* eA0 = &Al[(w*32     ) * 32];
    unsigned short* eA1 = &Al[(w*32 + 16) * 32];
    unsigned short* dB0 = &Bh[(w*32     ) * 32];
    unsigned short* dB1 = &Bh[(w*32 + 16) * 32];
    unsigned short* eB0 = &Bl[(w*32     ) * 32];
    unsigned short* eB1 = &Bl[(w*32 + 16) * 32];

    f4v acc[4][4];
    #pragma unroll
    for (int i = 0; i < 4; ++i)
      #pragma unroll
      for (int j = 0; j < 4; ++j) acc[i][j] = (f4v){0.f, 0.f, 0.f, 0.f};

    for (int kt = 0; kt < 1024; kt += 32) {
        __syncthreads();
        gload_lds16(hz + arow + kt,             dA0);
        gload_lds16(hz + arow + 16*1024 + kt,   dA1);
        gload_lds16(lz + arow + kt,             eA0);
        gload_lds16(lz + arow + 16*1024 + kt,   eA1);
        gload_lds16(hz + brow + kt,             dB0);
        gload_lds16(hz + brow + 16*1024 + kt,   dB1);
        gload_lds16(lz + brow + kt,             eB0);
        gload_lds16(lz + brow + 16*1024 + kt,   eB1);
        __syncthreads();

        s8v ah[4], al[4], bh[4], bl[4];
        #pragma unroll
        for (int i = 0; i < 4; ++i) {
            ah[i] = *(const s8v*)&Ah[(wm + i*16 + lrow) * 32 + quad * 8];
            al[i] = *(const s8v*)&Al[(wm + i*16 + lrow) * 32 + quad * 8];
        }
        #pragma unroll
        for (int j = 0; j < 4; ++j) {
            bh[j] = *(const s8v*)&Bh[(wn + j*16 + lrow) * 32 + quad * 8];
            bl[j] = *(const s8v*)&Bl[(wn + j*16 + lrow) * 32 + quad * 8];
        }
        #pragma unroll
        for (int i = 0; i < 4; ++i)
          #pragma unroll
          for (int j = 0; j < 4; ++j) {
              acc[i][j] = __builtin_amdgcn_mfma_f32_16x16x32_bf16(ah[i], bh[j], acc[i][j], 0, 0, 0);
              acc[i][j] = __builtin_amdgcn_mfma_f32_16x16x32_bf16(ah[i], bl[j], acc[i][j], 0, 0, 0);
              acc[i][j] = __builtin_amdgcn_mfma_f32_16x16x32_bf16(al[i], bh[j], acc[i][j], 0, 0, 0);
          }
    }

    float*          Cz  = C  + (size_t)z * MEG_;
    unsigned short* Cbz = Cb + (size_t)z * MEG_;
    #pragma unroll
    for (int i = 0; i < 4; ++i)
      #pragma unroll
      for (int j = 0; j < 4; ++j) {
        const int col = n0 + wn + j * 16 + lrow;
        #pragma unroll
        for (int r = 0; r < 4; ++r) {
            const int row = m0 + wm + i * 16 + quad * 4 + r;
            float v = acc[i][j][r];
            Cz [(size_t)row * 1024 + col] = v;
            Cbz[(size_t)row * 1024 + col] = f2bf(v);
        }
    }
}

// =====================================================================
// Pure-bf16 MFMA NT GEMM, 128x128 tile, BK=32, 256 thr (4 waves 2x2,
// each 64x64 via 4x4 mfma_16x16x32). global_load_lds dwordx4 staging,
// unpadded LDS [row][32] bf16. Dual-output column split at nsplit.
// z-batched via blockIdx.z with element strides zsA/zsB (shorts), zsC
// (floats; for OBF it is in floats of the underlying short buffer).
// mode: 0 plain, 1 scale by sptr[0]. OBF: write bf16 output.
// =====================================================================
template<bool OBF>
__global__ __launch_bounds__(256, 2) void gemm_bf16_t(
    const unsigned short* __restrict__ A,
    const unsigned short* __restrict__ B0, const unsigned short* __restrict__ B1,
    float* __restrict__ C0, float* __restrict__ C1,
    int K, int ldc0, int ldc1, int nsplit,
    long zsA, long zsB, long zsC,
    const float* __restrict__ sptr, int mode)
{
    __shared__ __align__(16) unsigned short As[128 * 32];
    __shared__ __align__(16) unsigned short Bs[128 * 32];
    const int tid = threadIdx.x;
    const int z   = blockIdx.z;
    const int m0  = blockIdx.y * 128;
    const int n0g = blockIdx.x * 128;

    const unsigned short* Az = A + (size_t)z * zsA;
    const unsigned short* Bsrc; float* Cp; int ldc; int c0;
    if (n0g < nsplit) {
        Bsrc = B0 + (size_t)z * zsB + (size_t)n0g * K;
        Cp = C0 + (size_t)z * zsC; ldc = ldc0; c0 = n0g;
    } else {
        Bsrc = B1 + (size_t)(n0g - nsplit) * K;
        Cp = C1; ldc = ldc1; c0 = n0g - nsplit;
    }

    const int lane = tid & 63;
    const int w    = tid >> 6;          // wave 0..3
    const int wm   = (w >> 1) * 64;
    const int wn   = (w & 1) * 64;
    const int lrow = lane & 15;
    const int quad = lane >> 4;

    const int srow = (lane >> 2);
    const int scol = (lane & 3) * 8;
    const unsigned short* Agl0 = Az   + (size_t)(m0 + w*32 + srow) * K + scol;
    const unsigned short* Agl1 = Agl0 + (size_t)16 * K;
    const unsigned short* Bgl0 = Bsrc + (size_t)(w*32 + srow) * K + scol;
    const unsigned short* Bgl1 = Bgl0 + (size_t)16 * K;
    unsigned short* lA0 = &As[(w*32     ) * 32];
    unsigned short* lA1 = &As[(w*32 + 16) * 32];
    unsigned short* lB0 = &Bs[(w*32     ) * 32];
    unsigned short* lB1 = &Bs[(w*32 + 16) * 32];

    f4v acc[4][4];
    #pragma unroll
    for (int i = 0; i < 4; ++i)
      #pragma unroll
      for (int j = 0; j < 4; ++j) acc[i][j] = (f4v){0.f, 0.f, 0.f, 0.f};

    for (int kt = 0; kt < K; kt += 32) {
        __syncthreads();                       // prev iter's LDS reads done
        gload_lds16(Agl0 + kt, lA0);
        gload_lds16(Agl1 + kt, lA1);
        gload_lds16(Bgl0 + kt, lB0);
        gload_lds16(Bgl1 + kt, lB1);
        __syncthreads();                       // drains vmcnt before barrier

        s8v af[4], bf[4];
        #pragma unroll
        for (int i = 0; i < 4; ++i)
            af[i] = *(const s8v*)&As[(wm + i*16 + lrow) * 32 + quad * 8];
        #pragma unroll
        for (int j = 0; j < 4; ++j)
            bf[j] = *(const s8v*)&Bs[(wn + j*16 + lrow) * 32 + quad * 8];
        #pragma unroll
        for (int i = 0; i < 4; ++i)
          #pragma unroll
          for (int j = 0; j < 4; ++j)
              acc[i][j] = __builtin_amdgcn_mfma_f32_16x16x32_bf16(af[i], bf[j], acc[i][j], 0, 0, 0);
    }

    float sc = (mode == 1) ? sptr[0] : 1.0f;

    // C/D layout: col = lane&15, row = quad*4 + reg  [m89-verified]
    #pragma unroll
    for (int i = 0; i < 4; ++i)
      #pragma unroll
      for (int j = 0; j < 4; ++j) {
        const int col = c0 + wn + j * 16 + lrow;
        #pragma unroll
        for (int r = 0; r < 4; ++r) {
            const int row = m0 + wm + i * 16 + quad * 4 + r;
            if (OBF)
                ((unsigned short*)Cp)[(size_t)row * ldc + col] = f2bf(acc[i][j][r] * sc);
            else
                Cp[(size_t)row * ldc + col] = acc[i][j][r] * sc;
        }
    }
}

// ---- pick column with max diagonal (dominant-eigvec seed), z=blockIdx.x ----
// Input is the bf16 S^64 from the squaring chain.
__global__ void pick_col(const unsigned short* __restrict__ Pall, float* __restrict__ vall)
{
    const unsigned short* P = Pall + (size_t)blockIdx.x * MEG_;
    float* v = vall + blockIdx.x * N_;
    __shared__ float sval[256];
    __shared__ int   sidx[256];
    __shared__ int   jstar;
    const int tid = threadIdx.x;
    float best = -1.f; int bidx = 0;
    for (int i = tid; i < N_; i += 256) {
        float d = bf2f(P[(size_t)i * (N_ + 1)]);
        if (d > best) { best = d; bidx = i; }
    }
    sval[tid] = best; sidx[tid] = bidx; __syncthreads();
    for (int off = 128; off > 0; off >>= 1) {
        if (tid < off && sval[tid + off] > sval[tid]) {
            sval[tid] = sval[tid + off]; sidx[tid] = sidx[tid + off];
        }
        __syncthreads();
    }
    if (tid == 0) jstar = sidx[0];
    __syncthreads();
    const int j = jstar;   // symmetric: row j == column j
    for (int i = tid; i < N_; i += 256) v[i] = bf2f(P[(size_t)j * N_ + i]);
}

// ---------------- w = G[z] * v[z] (one wave per row), z=blockIdx.y ----------
__global__ __launch_bounds__(256) void matvec_z(
    const float* __restrict__ Gall, const float* __restrict__ vall,
    float* __restrict__ wall)
{
    const int z = blockIdx.y;
    const float* G = Gall + (size_t)z * MEG_;
    const float* v = vall + z * N_;
    const int row  = blockIdx.x * 4 + (threadIdx.x >> 6);
    const int lane = threadIdx.x & 63;
    const float* g = G + (size_t)row * N_;
    float s = 0.f;
    for (int j = lane; j < N_; j += 64) s += g[j] * v[j];
    #pragma unroll
    for (int off = 32; off > 0; off >>= 1) s += __shfl_down(s, off, 64);
    if (lane == 0) wall[z * N_ + row] = s;
}

// ------- Rayleigh quotient -> inv_scale[z] = 1/max(sigma,1), z=blockIdx.x ----
__global__ void rq_scale(const float* __restrict__ w1a, const float* __restrict__ w2a,
                         float* __restrict__ slot)
{
    const int z = blockIdx.x;
    const float* w1 = w1a + z * N_;
    const float* w2 = w2a + z * N_;
    __shared__ float r11[256];
    __shared__ float r12[256];
    const int tid = threadIdx.x;
    float d11 = 0.f, d12 = 0.f;
    for (int i = tid; i < N_; i += 256) {
        float a = w1[i], b = w2[i];
        d11 = fmaf(a, a, d11);
        d12 = fmaf(a, b, d12);
    }
    r11[tid] = d11; r12[tid] = d12; __syncthreads();
    for (int off = 128; off > 0; off >>= 1) {
        if (tid < off) { r11[tid] += r11[tid + off]; r12[tid] += r12[tid + off]; }
        __syncthreads();
    }
    if (tid == 0) {
        float lam = r12[0] / fmaxf(r11[0], 1e-30f);
        float sig = sqrtf(fmaxf(lam, 0.f));
        slot[z] = 1.0f / fmaxf(sig, 1.0f);
    }
}

// ---------------- fast elementwise math (hw v_exp/v_log) ----------------
__device__ __forceinline__ float fast_sp(float x)   // softplus
{
    return fmaxf(x, 0.f) + __logf(1.0f + __expf(-fabsf(x)));
}
__device__ __forceinline__ float fast_tanh(float x)
{
    float e = __expf(2.0f * fabsf(x));
    float t = 1.0f - 2.0f / (e + 1.0f);
    return copysignf(t, x);
}

__device__ __forceinline__ void abc_math(
    float dr, float br, float cr, float uval,
    float alpha, float db, float sgain,
    float* pa, float* pbu, float* pc)
{
    float delta = fast_sp(dr + db);
    float a = fminf(__expf(-delta * alpha), 1.0f - 1e-4f);
    float b = fast_tanh(br);
    float c = fast_tanh(cr);
    float p = fmaf(a, a, c * c);
    float r = b * b;
    float q = a * b;
    float pr = p - r;
    float disc = fmaf(pr, pr, 4.0f * q * q);
    float lam = 0.5f * (p + r + sqrtf(disc + 1e-12f));
    float sig = sqrtf(lam + 1e-12f);
    float inv = 1.0f / fmaxf(sig, 1.0f);
    a *= inv; b *= inv; c *= inv;
    *pa = a; *pc = c; *pbu = b * (sgain * uval);
}

// --------- scan phase 1 (per stripe): per-chunk composite (CL=16) ---------
__global__ __launch_bounds__(256) void scan_phase1(
    const float* __restrict__ rawS, const float* __restrict__ usS,
    const float* __restrict__ bp, const float* __restrict__ dbias,
    const float* __restrict__ alog, const float* __restrict__ lgam,
    const float* __restrict__ inv_sin,
    float* __restrict__ agg_a, float* __restrict__ agg_b)
{
    const int gid = blockIdx.x * 256 + threadIdx.x;   // [0, CPS_*N_)
    const int n   = gid & (N_ - 1);
    const int cl  = gid >> 10;                        // local chunk 0..127

    const float alpha = fast_sp(alog[n]);
    const float db    = dbias[n];
    const float bpd   = bp[n];
    const float bpb   = bp[N_ + n];
    const float bpc   = bp[2*N_ + n];
    const float sgain = __expf(lgam[0]) * inv_sin[0];

    float Ap = 1.f, Bc = 0.f;
    size_t base  = (size_t)(cl * CL_) * K3_ + n;      // stripe-local
    size_t ubase = (size_t)(cl * CL_) * N_  + n;
    #pragma unroll 4
    for (int j = 0; j < CL_; ++j) {
        float dr = rawS[base]        + bpd;
        float br = rawS[base + N_]   + bpb;
        float cr = rawS[base + 2*N_] + bpc;
        float uv = usS[ubase];
        float a, bu, cv;
        abc_math(dr, br, cr, uv, alpha, db, sgain, &a, &bu, &cv);
        Bc = fmaf(a, Bc, bu);
        Ap *= a;
        base += K3_; ubase += N_;
    }
    agg_a[(size_t)cl * N_ + n] = Ap;
    agg_b[(size_t)cl * N_ + n] = Bc;
}

// --------- scan phase 2 (per stripe): chunk-prefix with inter-stripe carry ---
__global__ void scan_phase2s(const float* __restrict__ agg_a,
                             const float* __restrict__ agg_b,
                             float* __restrict__ pref, float* __restrict__ carry,
                             int bidx, int use_carry)
{
    const int n = blockIdx.x * 256 + threadIdx.x;     // 0..1023
    float z = use_carry ? carry[bidx * N_ + n] : 0.f;
    size_t idx = n;
    for (int c = 0; c < CPS_; ++c) {
        pref[idx] = z;
        z = fmaf(agg_a[idx], z, agg_b[idx]);
        idx += N_;
    }
    carry[bidx * N_ + n] = z;
}

// --------- scan phase 3 (per stripe): replay, write y_hat bf16 ---------
__global__ __launch_bounds__(256) void scan_phase3(
    const float* __restrict__ rawS, const float* __restrict__ usS,
    const float* __restrict__ bp, const float* __restrict__ dbias,
    const float* __restrict__ alog, const float* __restrict__ lgam,
    const float* __restrict__ inv_sin, const float* __restrict__ pref,
    unsigned short* __restrict__ yh)
{
    const int gid = blockIdx.x * 256 + threadIdx.x;
    const int n   = gid & (N_ - 1);
    const int cl  = gid >> 10;

    const float alpha = fast_sp(alog[n]);
    const float db    = dbias[n];
    const float bpd   = bp[n];
    const float bpb   = bp[N_ + n];
    const float bpc   = bp[2*N_ + n];
    const float sgain = __expf(lgam[0]) * inv_sin[0];

    float z = pref[(size_t)cl * N_ + n];
    size_t base  = (size_t)(cl * CL_) * K3_ + n;
    size_t ubase = (size_t)(cl * CL_) * N_  + n;
    #pragma unroll 4
    for (int j = 0; j < CL_; ++j) {
        float dr = rawS[base]        + bpd;
        float br = rawS[base + N_]   + bpb;
        float cr = rawS[base + 2*N_] + bpc;
        float uv = usS[ubase];
        float a, bu, cv;
        abc_math(dr, br, cr, uv, alpha, db, sgain, &a, &bu, &cv);
        yh[ubase] = f2bf(cv * z);          // y_hat[t] uses pre-update state
        z = fmaf(a, z, bu);
        base += K3_; ubase += N_;
    }
}

// =====================================================================
extern "C" void kernel_launch(void* const* d_in, const int* in_sizes, int n_in,
                              void* d_out, int out_size, void* d_ws, size_t ws_size,
                              hipStream_t stream)
{
    (void)in_sizes; (void)n_in;
    const float* u     = (const float*)d_in[0];
    const float* W_in  = (const float*)d_in[1];
    const float* W_out = (const float*)d_in[2];
    const float* Wp    = (const float*)d_in[3];
    const float* bp    = (const float*)d_in[4];
    const float* alog  = (const float*)d_in[5];
    const float* dbias = (const float*)d_in[6];
    const float* lgam  = (const float*)d_in[7];
    float* y = (float*)d_out;

    if (ws_size < (size_t)REQ_FLOATS * sizeof(float)) {
        zero_out<<<(out_size + 255) / 256, dim3(256), 0, stream>>>(y, out_size);
        return;
    }

    float* ws = (float*)d_ws;
    float*          rawS  = ws + OFF_RAWS;
    float*          usS   = ws + OFF_USS;
    unsigned short* ubf   = (unsigned short*)(ws + OFF_UBF);
    unsigned short* Wcat  = (unsigned short*)(ws + OFF_WCAT);
    unsigned short* Woutb = (unsigned short*)(ws + OFF_WOUTB);
    float* agg_a = ws + OFF_AGA;
    float* agg_b = ws + OFF_AGB;
    float* pref  = ws + OFF_PRE;
    float* carry = ws + OFF_CARRY;
    float* v0    = ws + OFF_V0;
    float* w1    = ws + OFF_W1;
    float* w2    = ws + OFF_W2;
    float* scal  = ws + OFF_SCAL;
    // sigma-phase aliases (live only before stripe processing)
    float*          G0   = rawS;                               // 2 x 1M f
    unsigned short* hiW  = (unsigned short*)(rawS + 2*MEG_);   // 2 x 1M shorts
    unsigned short* loW  = (unsigned short*)(rawS + 3*MEG_);   // 2 x 1M shorts
    unsigned short* SbfA = (unsigned short*)usS;               // 2 x 1M shorts
    unsigned short* SbfB = SbfA + 2*MEG_;                      // 2 x 1M shorts

    const dim3 blk(256);
    const int BIG = 1 << 30;

    cvt_weights<<<20480, blk, 0, stream>>>(W_in, Wp, W_out, Wcat, Woutb);

    // ---- spectral norms: split-bf16 MFMA gram (z=2), 6 bf16 squarings
    //      (unnormalized: bf16 exponent range covers lambda^64 ~ 4e13),
    //      then fp32 Rayleigh quotient on the MFMA-accurate G0. ----
    split_w<<<8192, blk, 0, stream>>>(W_in, W_out, hiW, loW);
    gram_bf16x2<<<dim3(8, 8, 2), blk, 0, stream>>>(hiW, loW, G0, SbfA);
    unsigned short* Sc = SbfA;
    unsigned short* Sn = SbfB;
    for (int r = 0; r < 6; ++r) {
        gemm_bf16_t<true><<<dim3(8, 8, 2), blk, 0, stream>>>(
            Sc, Sc, nullptr, (float*)Sn, nullptr,
            1024, 1024, 0, BIG, MEG_, MEG_, MEG_ / 2, nullptr, 0);
        unsigned short* t = Sc; Sc = Sn; Sn = t;
    }
    pick_col<<<2, blk, 0, stream>>>(Sc, v0);     // Sc == SbfA after 6 swaps
    matvec_z<<<dim3(256, 2), blk, 0, stream>>>(G0, v0, w1);
    matvec_z<<<dim3(256, 2), blk, 0, stream>>>(G0, w1, w2);
    rq_scale<<<2, blk, 0, stream>>>(w1, w2, scal);   // scal[0]=inv_in, scal[1]=inv_out

    // ---- single pass over stripes (sequential carry) ----
    for (int s = 0; s < NSTRIPE_; ++s) {
        const int r0 = s * SROWS_;
        cvt_u<<<8192, blk, 0, stream>>>(u + (size_t)r0 * DD_, ubf);
        // fused (W_in | Wp) gemm: cols < 1024 -> usS, cols >= 1024 -> rawS
        gemm_bf16_t<false><<<dim3(32, 16), blk, 0, stream>>>(
            ubf, Wcat, Wcat + (size_t)1024 * 1024, usS, rawS,
            1024, N_, K3_, 1024, 0, 0, 0, nullptr, 0);
        scan_phase1<<<512, blk, 0, stream>>>(rawS, usS, bp, dbias, alog, lgam,
                                             scal, agg_a, agg_b);
        scan_phase2s<<<4, blk, 0, stream>>>(agg_a, agg_b, pref, carry, s >> 1, s & 1);
        scan_phase3<<<512, blk, 0, stream>>>(rawS, usS, bp, dbias, alog, lgam,
                                             scal, pref, ubf);   // y_hat bf16 -> ubf
        gemm_bf16_t<false><<<dim3(8, 16), blk, 0, stream>>>(
            ubf, Woutb, nullptr, y + (size_t)r0 * N_, nullptr,
            1024, N_, 0, BIG, 0, 0, 0, scal + 1, 1);
    }
}

// Round 2
// 953.263 us; speedup vs baseline: 1.1988x; 1.1188x over previous
//
#include <hip/hip_runtime.h>

// ---------------- problem dims (fixed by setup_inputs) ----------------
#define B_    4
#define T_    4096
#define DD_   1024
#define N_    1024
#define K3_   3072
#define M_    16384      // B_*T_
#define CL_   16         // scan chunk length (time steps)
#define SROWS_ 2048      // stripe rows (one stripe = half a batch, aligned)
#define NSTRIPE_ (M_/SROWS_)     // 8
#define CPS_  (SROWS_/CL_)       // 128 chunks per stripe
#define MEG_  1048576

// ---------------- ws layout (float offsets), total ~47.6 MiB ----------------
// rawS (24 MiB) is aliased by the sigma phase: G0 (2M f) | hiW (1M f) | loW (1M f).
// usS (8 MiB) is aliased by the sigma phase: SbfA (2M shorts) | SbfB (2M shorts).
#define OFF_RAWS  ((size_t)0)                        // 6M f   (24 MiB)
#define OFF_USS   ((size_t)6*MEG_)                   // 2M f   (8 MiB)
#define OFF_UBF   ((size_t)8*MEG_)                   // 1M f = 2M shorts (u stripe bf16; later y_hat bf16)
#define OFF_WCAT  ((size_t)9*MEG_)                   // 2M f = 4M shorts (W_in rows then Wp rows)
#define OFF_WOUTB ((size_t)11*MEG_)                  // 512K f = 1M shorts
#define OFF_AGA   (OFF_WOUTB + 524288)               // 128K f
#define OFF_AGB   (OFF_AGA + 131072)
#define OFF_PRE   (OFF_AGB + 131072)
#define OFF_CARRY (OFF_PRE + 131072)                 // 4096 f
#define OFF_V0    (OFF_CARRY + 4096)                 // 2048 f (2 z)
#define OFF_W1    (OFF_V0 + 2048)
#define OFF_W2    (OFF_W1 + 2048)
#define OFF_TR    (OFF_W2 + 2048)                    // 16 f (unused, kept for layout)
#define OFF_SCAL  (OFF_TR + 16)                      // [0]=inv_in, [1]=inv_out
#define REQ_FLOATS (OFF_SCAL + 16)

typedef short s8v __attribute__((ext_vector_type(8)));   // 8 bf16 (4 VGPRs)
typedef float f4v __attribute__((ext_vector_type(4)));   // MFMA acc

typedef __attribute__((address_space(3))) unsigned int       lds_u32;
typedef const __attribute__((address_space(1))) unsigned int glb_u32;

__device__ __forceinline__ void gload_lds16(const void* g, void* l)
{
    __builtin_amdgcn_global_load_lds((glb_u32*)g, (lds_u32*)l, 16, 0, 0);
}

// fp32 -> bf16 round-to-nearest-even
__device__ __forceinline__ unsigned short f2bf(float f)
{
    unsigned u = __float_as_uint(f);
    u += 0x7FFFu + ((u >> 16) & 1u);
    return (unsigned short)(u >> 16);
}
__device__ __forceinline__ float bf2f(unsigned short h)
{
    return __uint_as_float((unsigned)h << 16);
}

// ---------------- fallback: zero a float buffer ----------------
__global__ void zero_out(float* __restrict__ y, int n)
{
    int i = blockIdx.x * 256 + threadIdx.x;
    if (i < n) y[i] = 0.f;
}

// ------- one-time weight conversion to bf16 + split-bf16 hi/lo planes -------
// Wcat = bf16(W_in | Wp), Woutb = bf16(W_out);
// hi/lo: [z=0] W_in, [z=1] W_out split as w = hi + lo (residual ~2^-18 rel).
__global__ void cvt_weights(const float* __restrict__ Win, const float* __restrict__ Wp,
                            const float* __restrict__ Wout,
                            unsigned short* __restrict__ Wcat,
                            unsigned short* __restrict__ Woutb,
                            unsigned short* __restrict__ hi,
                            unsigned short* __restrict__ lo)
{
    int i = blockIdx.x * 256 + threadIdx.x;        // 0 .. 5M-1
    if (i < 1048576)       Wcat[i] = f2bf(Win[i]);
    else if (i < 4194304)  Wcat[i] = f2bf(Wp[i - 1048576]);
    else if (i < 5242880)  Woutb[i - 4194304] = f2bf(Wout[i - 4194304]);
    if (i < 2097152) {
        float wv = (i < MEG_) ? Win[i] : Wout[i - MEG_];
        unsigned short h = f2bf(wv);
        hi[i] = h;
        lo[i] = f2bf(wv - bf2f(h));                // w - hi exact in fp32
    }
}

// ---------------- per-stripe u conversion ----------------
__global__ void cvt_u(const float* __restrict__ src, unsigned short* __restrict__ dst)
{
    int i = blockIdx.x * 256 + threadIdx.x;        // 0 .. 2M-1
    dst[i] = f2bf(src[i]);
}

// =====================================================================
// Split-bf16 MFMA gram: C[z] = W[z] W[z]^T computed as
//   hi.hi^T + hi.lo^T + lo.hi^T  (lo.lo dropped, ~2^-36 of diag).
// 64x64 tile (512 blocks -> occupancy), BK=32, 4 waves 2x2 x (2x2
// mfma_16x16x32). Writes fp32 C (Rayleigh quotient) AND bf16 Cb (chain seed).
// =====================================================================
__global__ __launch_bounds__(256, 4) void gram_bf16x2(
    const unsigned short* __restrict__ hi, const unsigned short* __restrict__ lo,
    float* __restrict__ C, unsigned short* __restrict__ Cb)
{
    __shared__ __align__(16) unsigned short Ah[64 * 32];
    __shared__ __align__(16) unsigned short Al[64 * 32];
    __shared__ __align__(16) unsigned short Bh[64 * 32];
    __shared__ __align__(16) unsigned short Bl[64 * 32];
    const int tid = threadIdx.x;
    const int z   = blockIdx.z;
    const int m0  = blockIdx.y * 64;
    const int n0  = blockIdx.x * 64;

    const unsigned short* hz = hi + (size_t)z * MEG_;
    const unsigned short* lz = lo + (size_t)z * MEG_;

    const int lane = tid & 63;
    const int w    = tid >> 6;
    const int wm   = (w >> 1) * 32;
    const int wn   = (w & 1) * 32;
    const int lrow = lane & 15;
    const int quad = lane >> 4;
    const int srow = lane >> 2;          // 16 rows per wave-load
    const int scol = (lane & 3) * 8;     // 4 x 16B granules per row

    const size_t arow = (size_t)(m0 + w*16 + srow) * 1024 + scol;
    const size_t brow = (size_t)(n0 + w*16 + srow) * 1024 + scol;
    unsigned short* dA = &Ah[(w*16) * 32];
    unsigned short* eA = &Al[(w*16) * 32];
    unsigned short* dB = &Bh[(w*16) * 32];
    unsigned short* eB = &Bl[(w*16) * 32];

    f4v acc[2][2];
    #pragma unroll
    for (int i = 0; i < 2; ++i)
      #pragma unroll
      for (int j = 0; j < 2; ++j) acc[i][j] = (f4v){0.f, 0.f, 0.f, 0.f};

    for (int kt = 0; kt < 1024; kt += 32) {
        __syncthreads();
        gload_lds16(hz + arow + kt, dA);
        gload_lds16(lz + arow + kt, eA);
        gload_lds16(hz + brow + kt, dB);
        gload_lds16(lz + brow + kt, eB);
        __syncthreads();

        s8v ah[2], al[2], bh[2], bl[2];
        #pragma unroll
        for (int i = 0; i < 2; ++i) {
            ah[i] = *(const s8v*)&Ah[(wm + i*16 + lrow) * 32 + quad * 8];
            al[i] = *(const s8v*)&Al[(wm + i*16 + lrow) * 32 + quad * 8];
        }
        #pragma unroll
        for (int j = 0; j < 2; ++j) {
            bh[j] = *(const s8v*)&Bh[(wn + j*16 + lrow) * 32 + quad * 8];
            bl[j] = *(const s8v*)&Bl[(wn + j*16 + lrow) * 32 + quad * 8];
        }
        #pragma unroll
        for (int i = 0; i < 2; ++i)
          #pragma unroll
          for (int j = 0; j < 2; ++j) {
              acc[i][j] = __builtin_amdgcn_mfma_f32_16x16x32_bf16(ah[i], bh[j], acc[i][j], 0, 0, 0);
              acc[i][j] = __builtin_amdgcn_mfma_f32_16x16x32_bf16(ah[i], bl[j], acc[i][j], 0, 0, 0);
              acc[i][j] = __builtin_amdgcn_mfma_f32_16x16x32_bf16(al[i], bh[j], acc[i][j], 0, 0, 0);
          }
    }

    float*          Cz  = C  + (size_t)z * MEG_;
    unsigned short* Cbz = Cb + (size_t)z * MEG_;
    #pragma unroll
    for (int i = 0; i < 2; ++i)
      #pragma unroll
      for (int j = 0; j < 2; ++j) {
        const int col = n0 + wn + j * 16 + lrow;
        #pragma unroll
        for (int r = 0; r < 4; ++r) {
            const int row = m0 + wm + i * 16 + quad * 4 + r;
            float v = acc[i][j][r];
            Cz [(size_t)row * 1024 + col] = v;
            Cbz[(size_t)row * 1024 + col] = f2bf(v);
        }
    }
}

// =====================================================================
// bf16 MFMA NT GEMM, 64x64 tile (high grid count for 1024-class shapes),
// BK=32, 4 waves 2x2, each 32x32 via 2x2 mfma_16x16x32. z-batched.
// OBF: bf16 output (zsC still in floats of the underlying buffer).
// mode: 0 plain, 1 scale by sptr[0].
// =====================================================================
template<bool OBF>
__global__ __launch_bounds__(256, 4) void gemm64_t(
    const unsigned short* __restrict__ A, const unsigned short* __restrict__ B,
    float* __restrict__ C, int K, int ldc,
    long zsA, long zsB, long zsC,
    const float* __restrict__ sptr, int mode)
{
    __shared__ __align__(16) unsigned short As[64 * 32];
    __shared__ __align__(16) unsigned short Bs[64 * 32];
    const int tid = threadIdx.x;
    const int z   = blockIdx.z;
    const int m0  = blockIdx.y * 64;
    const int n0  = blockIdx.x * 64;

    const unsigned short* Az = A + (size_t)z * zsA;
    const unsigned short* Bz = B + (size_t)z * zsB;

    const int lane = tid & 63;
    const int w    = tid >> 6;
    const int wm   = (w >> 1) * 32;
    const int wn   = (w & 1) * 32;
    const int lrow = lane & 15;
    const int quad = lane >> 4;
    const int srow = lane >> 2;
    const int scol = (lane & 3) * 8;

    const unsigned short* Agl = Az + (size_t)(m0 + w*16 + srow) * K + scol;
    const unsigned short* Bgl = Bz + (size_t)(n0 + w*16 + srow) * K + scol;
    unsigned short* lA = &As[(w*16) * 32];
    unsigned short* lB = &Bs[(w*16) * 32];

    f4v acc[2][2];
    #pragma unroll
    for (int i = 0; i < 2; ++i)
      #pragma unroll
      for (int j = 0; j < 2; ++j) acc[i][j] = (f4v){0.f, 0.f, 0.f, 0.f};

    for (int kt = 0; kt < K; kt += 32) {
        __syncthreads();
        gload_lds16(Agl + kt, lA);
        gload_lds16(Bgl + kt, lB);
        __syncthreads();

        s8v af[2], bf[2];
        #pragma unroll
        for (int i = 0; i < 2; ++i)
            af[i] = *(const s8v*)&As[(wm + i*16 + lrow) * 32 + quad * 8];
        #pragma unroll
        for (int j = 0; j < 2; ++j)
            bf[j] = *(const s8v*)&Bs[(wn + j*16 + lrow) * 32 + quad * 8];
        #pragma unroll
        for (int i = 0; i < 2; ++i)
          #pragma unroll
          for (int j = 0; j < 2; ++j)
              acc[i][j] = __builtin_amdgcn_mfma_f32_16x16x32_bf16(af[i], bf[j], acc[i][j], 0, 0, 0);
    }

    float sc = (mode == 1) ? sptr[0] : 1.0f;
    float* Cp = C + (size_t)z * zsC;

    // C/D layout: col = lane&15, row = quad*4 + reg  [m89-verified]
    #pragma unroll
    for (int i = 0; i < 2; ++i)
      #pragma unroll
      for (int j = 0; j < 2; ++j) {
        const int col = n0 + wn + j * 16 + lrow;
        #pragma unroll
        for (int r = 0; r < 4; ++r) {
            const int row = m0 + wm + i * 16 + quad * 4 + r;
            if (OBF)
                ((unsigned short*)Cp)[(size_t)row * ldc + col] = f2bf(acc[i][j][r] * sc);
            else
                Cp[(size_t)row * ldc + col] = acc[i][j][r] * sc;
        }
    }
}

// =====================================================================
// Pure-bf16 MFMA NT GEMM, 128x128 tile, BK=32, 256 thr (4 waves 2x2,
// each 64x64 via 4x4 mfma_16x16x32). Dual-output column split at nsplit.
// Used for the big per-stripe u-projection (grid 512 blocks).
// =====================================================================
__global__ __launch_bounds__(256, 2) void gemm_bf16(
    const unsigned short* __restrict__ A,
    const unsigned short* __restrict__ B0, const unsigned short* __restrict__ B1,
    float* __restrict__ C0, float* __restrict__ C1,
    int K, int ldc0, int ldc1, int nsplit)
{
    __shared__ __align__(16) unsigned short As[128 * 32];
    __shared__ __align__(16) unsigned short Bs[128 * 32];
    const int tid = threadIdx.x;
    const int m0  = blockIdx.y * 128;
    const int n0g = blockIdx.x * 128;

    const unsigned short* Bsrc; float* Cp; int ldc; int c0;
    if (n0g < nsplit) {
        Bsrc = B0 + (size_t)n0g * K;
        Cp = C0; ldc = ldc0; c0 = n0g;
    } else {
        Bsrc = B1 + (size_t)(n0g - nsplit) * K;
        Cp = C1; ldc = ldc1; c0 = n0g - nsplit;
    }

    const int lane = tid & 63;
    const int w    = tid >> 6;          // wave 0..3
    const int wm   = (w >> 1) * 64;
    const int wn   = (w & 1) * 64;
    const int lrow = lane & 15;
    const int quad = lane >> 4;

    const int srow = (lane >> 2);
    const int scol = (lane & 3) * 8;
    const unsigned short* Agl0 = A    + (size_t)(m0 + w*32 + srow) * K + scol;
    const unsigned short* Agl1 = Agl0 + (size_t)16 * K;
    const unsigned short* Bgl0 = Bsrc + (size_t)(w*32 + srow) * K + scol;
    const unsigned short* Bgl1 = Bgl0 + (size_t)16 * K;
    unsigned short* lA0 = &As[(w*32     ) * 32];
    unsigned short* lA1 = &As[(w*32 + 16) * 32];
    unsigned short* lB0 = &Bs[(w*32     ) * 32];
    unsigned short* lB1 = &Bs[(w*32 + 16) * 32];

    f4v acc[4][4];
    #pragma unroll
    for (int i = 0; i < 4; ++i)
      #pragma unroll
      for (int j = 0; j < 4; ++j) acc[i][j] = (f4v){0.f, 0.f, 0.f, 0.f};

    for (int kt = 0; kt < K; kt += 32) {
        __syncthreads();                       // prev iter's LDS reads done
        gload_lds16(Agl0 + kt, lA0);
        gload_lds16(Agl1 + kt, lA1);
        gload_lds16(Bgl0 + kt, lB0);
        gload_lds16(Bgl1 + kt, lB1);
        __syncthreads();                       // drains vmcnt before barrier

        s8v af[4], bf[4];
        #pragma unroll
        for (int i = 0; i < 4; ++i)
            af[i] = *(const s8v*)&As[(wm + i*16 + lrow) * 32 + quad * 8];
        #pragma unroll
        for (int j = 0; j < 4; ++j)
            bf[j] = *(const s8v*)&Bs[(wn + j*16 + lrow) * 32 + quad * 8];
        #pragma unroll
        for (int i = 0; i < 4; ++i)
          #pragma unroll
          for (int j = 0; j < 4; ++j)
              acc[i][j] = __builtin_amdgcn_mfma_f32_16x16x32_bf16(af[i], bf[j], acc[i][j], 0, 0, 0);
    }

    // C/D layout: col = lane&15, row = quad*4 + reg  [m89-verified]
    #pragma unroll
    for (int i = 0; i < 4; ++i)
      #pragma unroll
      for (int j = 0; j < 4; ++j) {
        const int col = c0 + wn + j * 16 + lrow;
        #pragma unroll
        for (int r = 0; r < 4; ++r) {
            const int row = m0 + wm + i * 16 + quad * 4 + r;
            Cp[(size_t)row * ldc + col] = acc[i][j][r];
        }
    }
}

// ---- pick column with max diagonal (dominant-eigvec seed), z=blockIdx.x ----
// Input is the bf16 S^64 from the squaring chain.
__global__ void pick_col(const unsigned short* __restrict__ Pall, float* __restrict__ vall)
{
    const unsigned short* P = Pall + (size_t)blockIdx.x * MEG_;
    float* v = vall + blockIdx.x * N_;
    __shared__ float sval[256];
    __shared__ int   sidx[256];
    __shared__ int   jstar;
    const int tid = threadIdx.x;
    float best = -1.f; int bidx = 0;
    for (int i = tid; i < N_; i += 256) {
        float d = bf2f(P[(size_t)i * (N_ + 1)]);
        if (d > best) { best = d; bidx = i; }
    }
    sval[tid] = best; sidx[tid] = bidx; __syncthreads();
    for (int off = 128; off > 0; off >>= 1) {
        if (tid < off && sval[tid + off] > sval[tid]) {
            sval[tid] = sval[tid + off]; sidx[tid] = sidx[tid + off];
        }
        __syncthreads();
    }
    if (tid == 0) jstar = sidx[0];
    __syncthreads();
    const int j = jstar;   // symmetric: row j == column j
    for (int i = tid; i < N_; i += 256) v[i] = bf2f(P[(size_t)j * N_ + i]);
}

// ---------------- w = G[z] * v[z] (one wave per row), z=blockIdx.y ----------
__global__ __launch_bounds__(256) void matvec_z(
    const float* __restrict__ Gall, const float* __restrict__ vall,
    float* __restrict__ wall)
{
    const int z = blockIdx.y;
    const float* G = Gall + (size_t)z * MEG_;
    const float* v = vall + z * N_;
    const int row  = blockIdx.x * 4 + (threadIdx.x >> 6);
    const int lane = threadIdx.x & 63;
    const float* g = G + (size_t)row * N_;
    float s = 0.f;
    for (int j = lane; j < N_; j += 64) s += g[j] * v[j];
    #pragma unroll
    for (int off = 32; off > 0; off >>= 1) s += __shfl_down(s, off, 64);
    if (lane == 0) wall[z * N_ + row] = s;
}

// ------- Rayleigh quotient -> inv_scale[z] = 1/max(sigma,1), z=blockIdx.x ----
__global__ void rq_scale(const float* __restrict__ w1a, const float* __restrict__ w2a,
                         float* __restrict__ slot)
{
    const int z = blockIdx.x;
    const float* w1 = w1a + z * N_;
    const float* w2 = w2a + z * N_;
    __shared__ float r11[256];
    __shared__ float r12[256];
    const int tid = threadIdx.x;
    float d11 = 0.f, d12 = 0.f;
    for (int i = tid; i < N_; i += 256) {
        float a = w1[i], b = w2[i];
        d11 = fmaf(a, a, d11);
        d12 = fmaf(a, b, d12);
    }
    r11[tid] = d11; r12[tid] = d12; __syncthreads();
    for (int off = 128; off > 0; off >>= 1) {
        if (tid < off) { r11[tid] += r11[tid + off]; r12[tid] += r12[tid + off]; }
        __syncthreads();
    }
    if (tid == 0) {
        float lam = r12[0] / fmaxf(r11[0], 1e-30f);
        float sig = sqrtf(fmaxf(lam, 0.f));
        slot[z] = 1.0f / fmaxf(sig, 1.0f);
    }
}

// ---------------- fast elementwise math (hw v_exp/v_log) ----------------
__device__ __forceinline__ float fast_sp(float x)   // softplus
{
    return fmaxf(x, 0.f) + __logf(1.0f + __expf(-fabsf(x)));
}
__device__ __forceinline__ float fast_tanh(float x)
{
    float e = __expf(2.0f * fabsf(x));
    float t = 1.0f - 2.0f / (e + 1.0f);
    return copysignf(t, x);
}

__device__ __forceinline__ void abc_math(
    float dr, float br, float cr, float uval,
    float alpha, float db, float sgain,
    float* pa, float* pbu, float* pc)
{
    float delta = fast_sp(dr + db);
    float a = fminf(__expf(-delta * alpha), 1.0f - 1e-4f);
    float b = fast_tanh(br);
    float c = fast_tanh(cr);
    float p = fmaf(a, a, c * c);
    float r = b * b;
    float q = a * b;
    float pr = p - r;
    float disc = fmaf(pr, pr, 4.0f * q * q);
    float lam = 0.5f * (p + r + sqrtf(disc + 1e-12f));
    float sig = sqrtf(lam + 1e-12f);
    float inv = 1.0f / fmaxf(sig, 1.0f);
    a *= inv; b *= inv; c *= inv;
    *pa = a; *pc = c; *pbu = b * (sgain * uval);
}

// --------- scan phase 1 (per stripe): per-chunk composite (CL=16) ---------
__global__ __launch_bounds__(256) void scan_phase1(
    const float* __restrict__ rawS, const float* __restrict__ usS,
    const float* __restrict__ bp, const float* __restrict__ dbias,
    const float* __restrict__ alog, const float* __restrict__ lgam,
    const float* __restrict__ inv_sin,
    float* __restrict__ agg_a, float* __restrict__ agg_b)
{
    const int gid = blockIdx.x * 256 + threadIdx.x;   // [0, CPS_*N_)
    const int n   = gid & (N_ - 1);
    const int cl  = gid >> 10;                        // local chunk 0..127

    const float alpha = fast_sp(alog[n]);
    const float db    = dbias[n];
    const float bpd   = bp[n];
    const float bpb   = bp[N_ + n];
    const float bpc   = bp[2*N_ + n];
    const float sgain = __expf(lgam[0]) * inv_sin[0];

    float Ap = 1.f, Bc = 0.f;
    size_t base  = (size_t)(cl * CL_) * K3_ + n;      // stripe-local
    size_t ubase = (size_t)(cl * CL_) * N_  + n;
    #pragma unroll 4
    for (int j = 0; j < CL_; ++j) {
        float dr = rawS[base]        + bpd;
        float br = rawS[base + N_]   + bpb;
        float cr = rawS[base + 2*N_] + bpc;
        float uv = usS[ubase];
        float a, bu, cv;
        abc_math(dr, br, cr, uv, alpha, db, sgain, &a, &bu, &cv);
        Bc = fmaf(a, Bc, bu);
        Ap *= a;
        base += K3_; ubase += N_;
    }
    agg_a[(size_t)cl * N_ + n] = Ap;
    agg_b[(size_t)cl * N_ + n] = Bc;
}

// --------- scan phase 2 (per stripe): chunk-prefix with inter-stripe carry ---
__global__ void scan_phase2s(const float* __restrict__ agg_a,
                             const float* __restrict__ agg_b,
                             float* __restrict__ pref, float* __restrict__ carry,
                             int bidx, int use_carry)
{
    const int n = blockIdx.x * 256 + threadIdx.x;     // 0..1023
    float z = use_carry ? carry[bidx * N_ + n] : 0.f;
    size_t idx = n;
    for (int c = 0; c < CPS_; ++c) {
        pref[idx] = z;
        z = fmaf(agg_a[idx], z, agg_b[idx]);
        idx += N_;
    }
    carry[bidx * N_ + n] = z;
}

// --------- scan phase 3 (per stripe): replay, write y_hat bf16 ---------
__global__ __launch_bounds__(256) void scan_phase3(
    const float* __restrict__ rawS, const float* __restrict__ usS,
    const float* __restrict__ bp, const float* __restrict__ dbias,
    const float* __restrict__ alog, const float* __restrict__ lgam,
    const float* __restrict__ inv_sin, const float* __restrict__ pref,
    unsigned short* __restrict__ yh)
{
    const int gid = blockIdx.x * 256 + threadIdx.x;
    const int n   = gid & (N_ - 1);
    const int cl  = gid >> 10;

    const float alpha = fast_sp(alog[n]);
    const float db    = dbias[n];
    const float bpd   = bp[n];
    const float bpb   = bp[N_ + n];
    const float bpc   = bp[2*N_ + n];
    const float sgain = __expf(lgam[0]) * inv_sin[0];

    float z = pref[(size_t)cl * N_ + n];
    size_t base  = (size_t)(cl * CL_) * K3_ + n;
    size_t ubase = (size_t)(cl * CL_) * N_  + n;
    #pragma unroll 4
    for (int j = 0; j < CL_; ++j) {
        float dr = rawS[base]        + bpd;
        float br = rawS[base + N_]   + bpb;
        float cr = rawS[base + 2*N_] + bpc;
        float uv = usS[ubase];
        float a, bu, cv;
        abc_math(dr, br, cr, uv, alpha, db, sgain, &a, &bu, &cv);
        yh[ubase] = f2bf(cv * z);          // y_hat[t] uses pre-update state
        z = fmaf(a, z, bu);
        base += K3_; ubase += N_;
    }
}

// =====================================================================
extern "C" void kernel_launch(void* const* d_in, const int* in_sizes, int n_in,
                              void* d_out, int out_size, void* d_ws, size_t ws_size,
                              hipStream_t stream)
{
    (void)in_sizes; (void)n_in;
    const float* u     = (const float*)d_in[0];
    const float* W_in  = (const float*)d_in[1];
    const float* W_out = (const float*)d_in[2];
    const float* Wp    = (const float*)d_in[3];
    const float* bp    = (const float*)d_in[4];
    const float* alog  = (const float*)d_in[5];
    const float* dbias = (const float*)d_in[6];
    const float* lgam  = (const float*)d_in[7];
    float* y = (float*)d_out;

    if (ws_size < (size_t)REQ_FLOATS * sizeof(float)) {
        zero_out<<<(out_size + 255) / 256, dim3(256), 0, stream>>>(y, out_size);
        return;
    }

    float* ws = (float*)d_ws;
    float*          rawS  = ws + OFF_RAWS;
    float*          usS   = ws + OFF_USS;
    unsigned short* ubf   = (unsigned short*)(ws + OFF_UBF);
    unsigned short* Wcat  = (unsigned short*)(ws + OFF_WCAT);
    unsigned short* Woutb = (unsigned short*)(ws + OFF_WOUTB);
    float* agg_a = ws + OFF_AGA;
    float* agg_b = ws + OFF_AGB;
    float* pref  = ws + OFF_PRE;
    float* carry = ws + OFF_CARRY;
    float* v0    = ws + OFF_V0;
    float* w1    = ws + OFF_W1;
    float* w2    = ws + OFF_W2;
    float* scal  = ws + OFF_SCAL;
    // sigma-phase aliases (live only before stripe processing)
    float*          G0   = rawS;                               // 2 x 1M f
    unsigned short* hiW  = (unsigned short*)(rawS + 2*MEG_);   // 2 x 1M shorts
    unsigned short* loW  = (unsigned short*)(rawS + 3*MEG_);   // 2 x 1M shorts
    unsigned short* SbfA = (unsigned short*)usS;               // 2 x 1M shorts
    unsigned short* SbfB = SbfA + 2*MEG_;                      // 2 x 1M shorts

    const dim3 blk(256);

    cvt_weights<<<20480, blk, 0, stream>>>(W_in, Wp, W_out, Wcat, Woutb, hiW, loW);

    // ---- spectral norms: split-bf16 MFMA gram (z=2), 6 bf16 squarings
    //      (unnormalized: bf16 exponent range covers lambda^64 ~ 4e13),
    //      then fp32 Rayleigh quotient on the MFMA-accurate G0. ----
    gram_bf16x2<<<dim3(16, 16, 2), blk, 0, stream>>>(hiW, loW, G0, SbfA);
    unsigned short* Sc = SbfA;
    unsigned short* Sn = SbfB;
    for (int r = 0; r < 6; ++r) {
        gemm64_t<true><<<dim3(16, 16, 2), blk, 0, stream>>>(
            Sc, Sc, (float*)Sn, 1024, 1024, MEG_, MEG_, MEG_ / 2, nullptr, 0);
        unsigned short* t = Sc; Sc = Sn; Sn = t;
    }
    pick_col<<<2, blk, 0, stream>>>(Sc, v0);     // Sc == SbfA after 6 swaps
    matvec_z<<<dim3(256, 2), blk, 0, stream>>>(G0, v0, w1);
    matvec_z<<<dim3(256, 2), blk, 0, stream>>>(G0, w1, w2);
    rq_scale<<<2, blk, 0, stream>>>(w1, w2, scal);   // scal[0]=inv_in, scal[1]=inv_out

    // ---- single pass over stripes (sequential carry) ----
    for (int s = 0; s < NSTRIPE_; ++s) {
        const int r0 = s * SROWS_;
        cvt_u<<<8192, blk, 0, stream>>>(u + (size_t)r0 * DD_, ubf);
        // fused (W_in | Wp) gemm: cols < 1024 -> usS, cols >= 1024 -> rawS
        gemm_bf16<<<dim3(32, 16), blk, 0, stream>>>(
            ubf, Wcat, Wcat + (size_t)1024 * 1024, usS, rawS,
            1024, N_, K3_, 1024);
        scan_phase1<<<512, blk, 0, stream>>>(rawS, usS, bp, dbias, alog, lgam,
                                             scal, agg_a, agg_b);
        scan_phase2s<<<4, blk, 0, stream>>>(agg_a, agg_b, pref, carry, s >> 1, s & 1);
        scan_phase3<<<512, blk, 0, stream>>>(rawS, usS, bp, dbias, alog, lgam,
                                             scal, pref, ubf);   // y_hat bf16 -> ubf
        gemm64_t<false><<<dim3(16, 32, 1), blk, 0, stream>>>(
            ubf, Woutb, y + (size_t)r0 * N_, 1024, 1024,
            0, 0, 0, scal + 1, 1);
    }
}